// Round 2
// baseline (1244.386 us; speedup 1.0000x reference)
//
#include <hip/hip_runtime.h>

typedef unsigned short u16;
typedef __attribute__((ext_vector_type(8))) short bf16x8;
typedef __attribute__((ext_vector_type(4))) float f32x4;
typedef __attribute__((ext_vector_type(4))) int   i32x4;

#define DEVFN static __device__ __forceinline__
#define AS_G __attribute__((address_space(1)))
#define AS_L __attribute__((address_space(3)))

DEVFN float b2f(u16 u){ return __uint_as_float(((unsigned int)u)<<16); }
DEVFN u16 f2b(float f){ unsigned int x = __float_as_uint(f); x += 0x7FFFu + ((x>>16)&1u); return (u16)(x>>16); }
DEVFN float fastrcp(float x){ return __builtin_amdgcn_rcpf(x); }

// ---------------------------------------------------------------------------
// fp32 -> bf16 cast (for weight tensors used as bf16 MFMA operands)
// ---------------------------------------------------------------------------
__global__ void castf2b(const float* __restrict__ s, u16* __restrict__ d, int n)
{
    int i = blockIdx.x*256 + threadIdx.x;
    if (i < n) d[i] = f2b(s[i]);
}

// ---------------------------------------------------------------------------
// whh fp32 -> i8 per-row quantization. One 64-lane wave per row of 128.
// ---------------------------------------------------------------------------
__global__ void quant_whh(const float* __restrict__ w, char* __restrict__ qw,
                          float* __restrict__ dq, int nrows)
{
    int row = blockIdx.x;
    int lane = threadIdx.x;
    if (row >= nrows) return;
    const float* wr = w + (long long)row*128;
    float v0 = wr[lane], v1 = wr[lane+64];
    float m = fmaxf(fabsf(v0), fabsf(v1));
#pragma unroll
    for (int off = 32; off; off >>= 1) m = fmaxf(m, __shfl_xor(m, off));
    float s = (m > 0.f) ? m * (1.f/127.f) : 1.f;
    float inv = 1.f / s;
    qw[(long long)row*128 + lane]      = (char)__float2int_rn(v0 * inv);
    qw[(long long)row*128 + lane + 64] = (char)__float2int_rn(v1 * inv);
    if (lane == 0) dq[row] = s * (1.f/127.f);
}

// ---------------------------------------------------------------------------
// Generic bf16 GEMM: C[M,N] = A[M,K] * B[N,K]^T (+bias[N]) (+PReLU) (+GN stats)
// Block remap: same-mTile blocks dispatch-adjacent for A-panel L2 reuse.
// ---------------------------------------------------------------------------
__global__ __launch_bounds__(256)
void gemm_bt(const u16* __restrict__ A, const u16* __restrict__ B,
             const float* __restrict__ bias, u16* __restrict__ C,
             int K, int N,
             long long zA, long long zB, long long zBias, long long zC,
             const float* __restrict__ alphaP, float* __restrict__ stats, int rowsPerB)
{
    __shared__ __align__(16) u16 As[128*32];
    __shared__ __align__(16) u16 Bs[128*32];
    __shared__ float sstat[16];

    const int tid  = threadIdx.x;
    const int wave = tid >> 6, lane = tid & 63;
    const int quad = lane >> 4, l16 = lane & 15;
    const int wm = wave & 1, wn = wave >> 1;
    const long long z = blockIdx.z;
    A += z * zA; B += z * zB; C += z * zC;
    if (bias) bias += z * zBias;
    // dispatch order is x-fastest; remap so the gridDim.y blocks sharing an
    // A-panel (same mTile) are dispatch-adjacent -> land on same XCD's L2.
    const int lin   = blockIdx.y * gridDim.x + blockIdx.x;
    const int mBase = (int)(lin / gridDim.y) * 128;
    const int nBase = (int)(lin % gridDim.y) * 128;

    f32x4 acc[4][4];
#pragma unroll
    for (int i = 0; i < 4; i++)
#pragma unroll
        for (int j = 0; j < 4; j++) acc[i][j] = (f32x4){0.f,0.f,0.f,0.f};

    const int srow = lane >> 2;
    const int sk   = (lane & 3) * 8;
    const int nK = K >> 5;

    for (int kk = 0; kk < nK; ++kk) {
        const int k0 = kk << 5;
#pragma unroll
        for (int q = 0; q < 2; q++) {
            const u16* ga = A + (long long)(mBase + wave*32 + q*16 + srow) * K + k0 + sk;
            const u16* gb = B + (long long)(nBase + wave*32 + q*16 + srow) * K + k0 + sk;
            __builtin_amdgcn_global_load_lds((const AS_G unsigned int*)ga,
                (AS_L unsigned int*)(As + (wave*32 + q*16)*32), 16, 0, 0);
            __builtin_amdgcn_global_load_lds((const AS_G unsigned int*)gb,
                (AS_L unsigned int*)(Bs + (wave*32 + q*16)*32), 16, 0, 0);
        }
        __syncthreads();
        bf16x8 af[4], bfr[4];
#pragma unroll
        for (int mt = 0; mt < 4; mt++) af[mt]  = *(const bf16x8*)(As + (wm*64 + mt*16 + l16)*32 + quad*8);
#pragma unroll
        for (int nt = 0; nt < 4; nt++) bfr[nt] = *(const bf16x8*)(Bs + (wn*64 + nt*16 + l16)*32 + quad*8);
#pragma unroll
        for (int mt = 0; mt < 4; mt++)
#pragma unroll
            for (int nt = 0; nt < 4; nt++)
                acc[mt][nt] = __builtin_amdgcn_mfma_f32_16x16x32_bf16(af[mt], bfr[nt], acc[mt][nt], 0, 0, 0);
        __syncthreads();
    }

    const bool doStats = (stats != nullptr);
    const float alpha = alphaP ? alphaP[0] : 0.f;
    if (doStats) { if (tid < 16) sstat[tid] = 0.f; __syncthreads(); }

    float lsum[4] = {0,0,0,0}, lsq[4] = {0,0,0,0};
#pragma unroll
    for (int nt = 0; nt < 4; nt++) {
        const int col = nBase + wn*64 + nt*16 + l16;
        const float bv = bias ? bias[col] : 0.f;
#pragma unroll
        for (int mt = 0; mt < 4; mt++) {
#pragma unroll
            for (int r = 0; r < 4; r++) {
                const int row = mBase + wm*64 + mt*16 + quad*4 + r;
                float v = acc[mt][nt][r] + bv;
                if (alphaP) v = v > 0.f ? v : alpha * v;
                C[(long long)row * N + col] = f2b(v);
                lsum[nt] += v; lsq[nt] += v * v;
            }
        }
    }
    if (doStats) {
#pragma unroll
        for (int nt = 0; nt < 4; nt++) {
            const int gn = wn*4 + nt;
            atomicAdd(&sstat[gn], lsum[nt]);
            atomicAdd(&sstat[8 + gn], lsq[nt]);
        }
        __syncthreads();
        if (tid < 16) {
            const int b = mBase / rowsPerB;
            atomicAdd(&stats[b*16 + tid], sstat[tid]);
        }
    }
}

// ---------------------------------------------------------------------------
// GRU recurrence (i8 MFMA core), chunk-parallel.
// NCHUNK=24: 384 blocks -> ~1.5 blocks/CU co-resident; per-block max steps
// 192 (96 warm + 96 owned). Per-step sync is a raw lgkmcnt-drain + s_barrier
// (LDS ordering only) so burst-prefetch global loads stay in flight across
// steps. MFMA pairs de-chained (only lane element [0] is consumed; integer
// add is exact).
// ---------------------------------------------------------------------------
#define HSB 144     // h row stride in bytes (128 i8 + 16 pad, 16B aligned)
#define BURST 16
#define NCHUNK 24
#define CHUNK  96   // 2304 / NCHUNK; multiple of 2*BURST
#define WARM   96   // warm-up steps; multiple of 2*BURST

__global__ __launch_bounds__(512, 2)
void gru_rec(const u16* __restrict__ gxH, const u16* __restrict__ gxV,
             const char* __restrict__ qwH, const char* __restrict__ qwV,
             const float* __restrict__ dqH, const float* __restrict__ dqV,
             const float* __restrict__ bhhH, const float* __restrict__ bhhV,
             u16* __restrict__ outH, u16* __restrict__ outV)
{
    const int id    = blockIdx.x / NCHUNK;   // (stack, group, dir)
    const int chunk = blockIdx.x % NCHUNK;
    const int stack = id >> 3, g = (id >> 1) & 3, d = id & 1;
    const u16*  gx  = (stack ? gxV : gxH) + (long long)g*9216*768 + d*384;
    const char* qw  = (stack ? qwV : qwH) + (long long)(g*2 + d)*384*128;
    const float* dqv = (stack ? dqV : dqH) + (g*2 + d)*384;
    const float* bhh = (stack ? bhhV : bhhH) + (g*2 + d)*384;
    u16* out = (stack ? outV : outH) + (long long)g*9216*256 + d*128;

    const int sBegin = chunk * CHUNK;        // first step whose output we own
    const int sEnd   = sBegin + CHUNK;       // one past last
    const int sw     = (chunk == 0) ? 0 : sBegin - WARM;  // warm-up start

    const int tid = threadIdx.x;
    const int w = tid >> 6, lane = tid & 63;
    const int quad = lane >> 4, l16 = lane & 15;

    __shared__ __align__(16) char hbf8[2][16*HSB];   // 4.6 KB
    __shared__ __align__(16) u16 outs[2][BURST*512]; // 32 KB
    for (int i = tid; i < 2*16*HSB; i += 512) ((char*)hbf8)[i] = 0;

    const int col = w*16 + l16;
    i32x4 ifrag[3][2];
#pragma unroll
    for (int gate = 0; gate < 3; ++gate)
#pragma unroll
        for (int kc = 0; kc < 2; ++kc)
            ifrag[gate][kc] = *(const i32x4*)(qw + (long long)(gate*128 + col)*128 + kc*64 + quad*16);

    const float dqR = dqv[col], dqZ = dqv[128 + col], dqN = dqv[256 + col];
    const float bhr = bhh[col], bhz = bhh[128 + col], bhn = bhh[256 + col];
    float h = 0.f;

    const int step = d ? -1 : 1;
    const int t0 = d ? 2303 : 0;
    const long long rowStride = (long long)step * 3072;

    u16 bankA[BURST][3], bankB[BURST][3];
    const i32x4 zi = {0,0,0,0};

    auto loadBank = [&](u16 (&bk)[BURST][3], int sbase) {
        if (sbase >= sEnd) return;     // banks are 32-aligned: all-in or all-out
        const u16* p = gx + (long long)((t0 + step*sbase)*4 + quad)*768 + col;
#pragma unroll
        for (int j = 0; j < BURST; j++) {
            bk[j][0] = p[0]; bk[j][1] = p[128]; bk[j][2] = p[256];
            p += rowStride;
        }
    };

    auto flushOut = [&](int sbase, int bank) {
        const u16* ob = outs[bank];
#pragma unroll
        for (int c = 0; c < 2; c++) {
            const int lin = (tid + c*512) * 8;
            const int s   = lin >> 9;
            const int rem = lin & 511;
            const int q   = rem >> 7, cc = rem & 127;
            const int tt  = t0 + step * (sbase + s);
            *(uint4*)(out + (long long)(tt*4 + q)*256 + cc) = *(const uint4*)(ob + lin);
        }
    };

    // LDS-only barrier: drain this wave's ds ops, sync workgroup. Does NOT
    // drain vmcnt, so burst-prefetch global loads stay in flight.
    auto ldsbar = [&]() {
        asm volatile("s_waitcnt lgkmcnt(0)\n\ts_barrier" ::: "memory");
    };

    auto stepf = [&](int j, int bank, u16 g0, u16 g1, u16 g2) {
        const char* hb = hbf8[j & 1];
        char* hw = (char*)hbf8[(j + 1) & 1];
        i32x4 a0 = *(const i32x4*)(hb + l16*HSB + quad*16);
        i32x4 a1 = *(const i32x4*)(hb + l16*HSB + 64 + quad*16);
        // 6 independent MFMAs (zero accumulator); only lane elem [0] is used,
        // so the K-halves are summed with an exact integer add instead of
        // chaining through the accumulator (removes one MFMA latency).
        i32x4 aR0 = __builtin_amdgcn_mfma_i32_16x16x64_i8(a0, ifrag[0][0], zi, 0, 0, 0);
        i32x4 aZ0 = __builtin_amdgcn_mfma_i32_16x16x64_i8(a0, ifrag[1][0], zi, 0, 0, 0);
        i32x4 aN0 = __builtin_amdgcn_mfma_i32_16x16x64_i8(a0, ifrag[2][0], zi, 0, 0, 0);
        i32x4 aR1 = __builtin_amdgcn_mfma_i32_16x16x64_i8(a1, ifrag[0][1], zi, 0, 0, 0);
        i32x4 aZ1 = __builtin_amdgcn_mfma_i32_16x16x64_i8(a1, ifrag[1][1], zi, 0, 0, 0);
        i32x4 aN1 = __builtin_amdgcn_mfma_i32_16x16x64_i8(a1, ifrag[2][1], zi, 0, 0, 0);
        const int iR = aR0[0] + aR1[0];
        const int iZ = aZ0[0] + aZ1[0];
        const int iN = aN0[0] + aN1[0];
        // lane holds C[row = 4*quad (reg 0)][col = l16] -> (batch quad, this col)
        float r  = fastrcp(1.f + __expf(-(b2f(g0) + bhr + (float)iR * dqR)));
        float zz = fastrcp(1.f + __expf(-(b2f(g1) + bhz + (float)iZ * dqZ)));
        float nn = b2f(g2) + r * ((float)iN * dqN + bhn);
        nn = 1.f - 2.f * fastrcp(__expf(2.f * nn) + 1.f);   // tanh
        h = zz * (h - nn) + nn;
        hw[4*quad*HSB + col] = (char)__float2int_rn(h * 127.f);
        outs[bank][j*512 + quad*128 + col] = f2b(h);
        ldsbar();
    };

    loadBank(bankA, sw);
    __syncthreads();   // hbf8 zero visible + bankA drained

    for (int base = sw; base < sEnd; base += 2*BURST) {
        loadBank(bankB, base + BURST);
#pragma unroll
        for (int j = 0; j < BURST; j++) stepf(j, 0, bankA[j][0], bankA[j][1], bankA[j][2]);
        if (base >= sBegin) flushOut(base, 0);
        loadBank(bankA, base + 2*BURST);
#pragma unroll
        for (int j = 0; j < BURST; j++) stepf(j, 1, bankB[j][0], bankB[j][1], bankB[j][2]);
        if (base + BURST >= sBegin) flushOut(base + BURST, 1);
    }
}

// ---------------------------------------------------------------------------
// Small helper kernels (fp32 external boundaries)
// ---------------------------------------------------------------------------
__global__ void repack_w(const float* __restrict__ w1, const float* __restrict__ w2,
                         const float* __restrict__ wc,
                         u16* __restrict__ w1r, u16* __restrict__ w2r, u16* __restrict__ wcr)
{
    int idx = blockIdx.x*256 + threadIdx.x;
    if (idx < 128*1152) {
        int o = idx / 1152, k = idx % 1152, tap = k >> 7, ci = k & 127;
        w2r[idx] = f2b(w2[(o*128 + ci)*9 + tap]);
    }
    if (idx < 128*32) {
        int o = idx >> 5, k = idx & 31;
        float v = 0.f;
        if (k < 27) { int tap = k/3, ci = k - tap*3; v = w1[(o*3 + ci)*9 + tap]; }
        w1r[idx] = f2b(v);
    }
    if (idx < 128*256) wcr[idx] = f2b(wc[idx]);
}

__global__ void im2col1(const float* __restrict__ x, u16* __restrict__ A1)
{
    int row = blockIdx.x*256 + threadIdx.x;
    if (row >= 36864) return;
    int b = row / 9216, rem = row % 9216, m = rem / 96, n = rem % 96;
    u16* dst = A1 + (long long)row*32;
#pragma unroll
    for (int k = 0; k < 32; k++) {
        float v = 0.f;
        if (k < 27) {
            int tap = k/3, ci = k - tap*3;
            int mm = m + tap/3 - 1, nn = n + tap%3 - 1;
            if (mm >= 0 && mm < 96 && nn >= 0 && nn < 96)
                v = x[((b*3 + ci)*96 + mm)*96 + nn];
        }
        dst[k] = f2b(v);
    }
}

__global__ void make_ss(const float* __restrict__ stats, const float* __restrict__ gw,
                        const float* __restrict__ gb, float* __restrict__ sc,
                        float* __restrict__ sh, float invCnt)
{
    int idx = blockIdx.x*256 + threadIdx.x;
    if (idx >= 512) return;
    int b = idx >> 7, c = idx & 127, gn = c >> 4;
    float s = stats[b*16 + gn], q = stats[b*16 + 8 + gn];
    float mu = s * invCnt, var = fmaxf(q * invCnt - mu*mu, 0.f);
    float rstd = rsqrtf(var + 1e-5f);
    float scale = rstd * gw[c];
    sc[idx] = scale;
    sh[idx] = gb[c] - mu * scale;
}

__global__ void im2col2(const u16* __restrict__ buf1, const float* __restrict__ sc,
                        const float* __restrict__ sh, u16* __restrict__ A2)
{
    long long idx = (long long)blockIdx.x*256 + threadIdx.x;
    if (idx >= (long long)36864*1152) return;
    int row = (int)(idx / 1152), k = (int)(idx % 1152);
    int tap = k >> 7, ci = k & 127;
    int b = row / 9216, rem = row % 9216, m = rem / 96, n = rem % 96;
    int mm = m + tap/3 - 1, nn = n + tap%3 - 1;
    u16 v = 0;
    if (mm >= 0 && mm < 96 && nn >= 0 && nn < 96) {
        float f = b2f(buf1[(long long)(b*9216 + mm*96 + nn)*128 + ci]);
        v = f2b(f * sc[b*128 + ci] + sh[b*128 + ci]);
    }
    A2[idx] = v;
}

__global__ void repack_seq(const u16* __restrict__ buf2, const float* __restrict__ sc,
                           const float* __restrict__ sh, u16* __restrict__ xh, u16* __restrict__ xv)
{
    int idx = blockIdx.x*256 + threadIdx.x;
    if (idx >= 4718592) return;
    int c = idx & 127, r1 = idx >> 7;
    int b = r1 & 3, r2 = r1 >> 2;
    int t = r2 % 2304, g = r2 / 2304;
    int iw = t / 96, pos = t % 96;
    float scale = sc[b*128 + c], shift = sh[b*128 + c];
    int rowH = b*9216 + (g*24 + iw)*96 + pos;
    int rowV = b*9216 + pos*96 + (g*24 + iw);
    xh[idx] = f2b(b2f(buf2[(long long)rowH*128 + c]) * scale + shift);
    xv[idx] = f2b(b2f(buf2[(long long)rowV*128 + c]) * scale + shift);
}

__global__ void repack_B(const u16* __restrict__ z1H, const u16* __restrict__ z1V,
                         u16* __restrict__ xh2, u16* __restrict__ xv2)
{
    int idx = blockIdx.x*256 + threadIdx.x;
    if (idx >= 4718592) return;
    int c = idx & 127, r1 = idx >> 7;
    int b = r1 & 3, r2 = r1 >> 2;
    int t = r2 % 2304, g = r2 / 2304;
    {
        int ih2 = t / 96, n = t % 96, gs = n / 24, iv = n % 24;
        long long s = ((long long)gs*9216 + (iv*96 + g*24 + ih2)*4 + b)*256 + c;
        xh2[idx] = f2b(0.5f*(b2f(z1V[s]) + b2f(z1V[s + 128])));
    }
    {
        int iv = t / 96, m = t % 96, gs = m / 24, ih = m % 24;
        long long s = ((long long)gs*9216 + (ih*96 + g*24 + iv)*4 + b)*256 + c;
        xv2[idx] = f2b(0.5f*(b2f(z1H[s]) + b2f(z1H[s + 128])));
    }
}

__global__ void repack_comb(const u16* __restrict__ z1H, const u16* __restrict__ z1V,
                            u16* __restrict__ Ac)
{
    long long idx = (long long)blockIdx.x*256 + threadIdx.x;
    if (idx >= (long long)36864*256) return;
    int k = (int)(idx & 255);
    int row = (int)(idx >> 8);
    int b = row / 9216, rem = row % 9216, m = rem / 96, n = rem % 96;
    float v;
    if (k < 128) {
        int g = m / 24, ih = m % 24, ts = ih*96 + n;
        long long s = ((long long)g*9216 + ts*4 + b)*256 + k;
        v = 0.5f*(b2f(z1H[s]) + b2f(z1H[s + 128]));
    } else {
        int c = k - 128, g = n / 24, iv = n % 24, ts = iv*96 + m;
        long long s = ((long long)g*9216 + ts*4 + b)*256 + c;
        v = 0.5f*(b2f(z1V[s]) + b2f(z1V[s + 128]));
    }
    Ac[idx] = f2b(v);
}

__global__ void final_kernel(const u16* __restrict__ p3, const float* __restrict__ sc,
                             const float* __restrict__ sh, float* __restrict__ out)
{
    __shared__ float tile[128*97];
    int bm = blockIdx.x;
    int b = bm / 96, m = bm % 96;
    int tid = threadIdx.x;
    int rowbase = b*9216 + m*96;
    for (int idx = tid; idx < 96*128; idx += 256) {
        int n = idx >> 7, o = idx & 127;
        float v = b2f(p3[(long long)(rowbase + n)*128 + o]);
        tile[o*97 + n] = v * sc[b*128 + o] + sh[b*128 + o];
    }
    __syncthreads();
    for (int idx = tid; idx < 96*128; idx += 256) {
        int o = idx / 96, n = idx % 96;
        out[((long long)(b*128 + o)*96 + m)*96 + n] = tile[o*97 + n];
    }
}

// ---------------------------------------------------------------------------
extern "C" void kernel_launch(void* const* d_in, const int* in_sizes, int n_in,
                              void* d_out, int out_size, void* d_ws, size_t ws_size,
                              hipStream_t stream)
{
    (void)in_sizes; (void)n_in; (void)out_size;
    auto F = [&](int i){ return (const float*)d_in[i]; };

    char* ws = (char*)d_ws;
    size_t off = 0;
    auto alloc = [&](size_t bytes)->char* {
        char* p = ws + off;
        off += (bytes + 255) & ~(size_t)255;
        return p;
    };

    float* stats = (float*)alloc(3*64*sizeof(float));
    float* sc1 = (float*)alloc(512*4); float* sh1 = (float*)alloc(512*4);
    float* sc2 = (float*)alloc(512*4); float* sh2 = (float*)alloc(512*4);
    float* sc3 = (float*)alloc(512*4); float* sh3 = (float*)alloc(512*4);
    u16* w1r  = (u16*)alloc((size_t)128*32*2);
    u16* w2r  = (u16*)alloc((size_t)128*1152*2);
    u16* wcr  = (u16*)alloc((size_t)128*256*2);
    u16 *wih0c[4], *wih1c[4];
    char *qw0[4], *qw1[4];
    float *dq0[4], *dq1[4];
    for (int p = 0; p < 4; p++) {
        wih0c[p] = (u16*)alloc((size_t)393216*2);
        wih1c[p] = (u16*)alloc((size_t)786432*2);
        qw0[p]   = (char*)alloc((size_t)393216);
        qw1[p]   = (char*)alloc((size_t)393216);
        dq0[p]   = (float*)alloc((size_t)3072*4);
        dq1[p]   = (float*)alloc((size_t)3072*4);
    }
    u16* A1   = (u16*)alloc((size_t)36864*32*2);
    u16* buf1 = (u16*)alloc((size_t)36864*128*2);
    u16* buf2 = (u16*)alloc((size_t)36864*128*2);
    u16* xh   = (u16*)alloc((size_t)4718592*2);
    u16* xv   = (u16*)alloc((size_t)4718592*2);
    u16* gxH  = (u16*)alloc((size_t)4*9216*768*2);
    u16* gxV  = (u16*)alloc((size_t)4*9216*768*2);
    u16* z1H  = (u16*)alloc((size_t)4*9216*256*2);
    u16* z1V  = (u16*)alloc((size_t)4*9216*256*2);

    u16* A2  = gxH;
    u16* y0H = xh;
    u16* y0V = buf1;
    u16* Ac  = xh;
    u16* p3  = buf1;

    if (ws_size < off) return;

    hipMemsetAsync(stats, 0, 3*64*sizeof(float), stream);
    repack_w<<<576, 256, 0, stream>>>(F(1), F(6), F(11), w1r, w2r, wcr);
    im2col1<<<144, 256, 0, stream>>>(F(0), A1);
    for (int p = 0; p < 4; p++) {
        int base = 16 + p*8;
        castf2b<<<(393216+255)/256, 256, 0, stream>>>(F(base+0), wih0c[p], 393216);
        castf2b<<<(786432+255)/256, 256, 0, stream>>>(F(base+4), wih1c[p], 786432);
        quant_whh<<<3072, 64, 0, stream>>>(F(base+1), qw0[p], dq0[p], 3072);
        quant_whh<<<3072, 64, 0, stream>>>(F(base+5), qw1[p], dq1[p], 3072);
    }

    gemm_bt<<<dim3(288,1,1), 256, 0, stream>>>(A1, w1r, F(2), buf1, 32, 128,
        0,0,0,0, F(3), stats + 0, 9216);
    make_ss<<<2, 256, 0, stream>>>(stats + 0, F(4), F(5), sc1, sh1, 1.f/147456.f);

    im2col2<<<165888, 256, 0, stream>>>(buf1, sc1, sh1, A2);
    gemm_bt<<<dim3(288,1,1), 256, 0, stream>>>(A2, w2r, F(7), buf2, 1152, 128,
        0,0,0,0, F(8), stats + 64, 9216);
    make_ss<<<2, 256, 0, stream>>>(stats + 64, F(9), F(10), sc2, sh2, 1.f/147456.f);

    repack_seq<<<18432, 256, 0, stream>>>(buf2, sc2, sh2, xh, xv);

    const long long zA0 = 9216LL*128, zA1 = 9216LL*256;
    const long long zB0 = 768LL*128,  zB1 = 768LL*256;
    const long long zC  = 9216LL*768;

    // ---- Stage A ----
    gemm_bt<<<dim3(72,6,4), 256, 0, stream>>>(xh, wih0c[0], F(18), gxH, 128, 768, zA0, zB0, 768, zC, nullptr, nullptr, 0);
    gemm_bt<<<dim3(72,6,4), 256, 0, stream>>>(xv, wih0c[1], F(26), gxV, 128, 768, zA0, zB0, 768, zC, nullptr, nullptr, 0);
    gru_rec<<<16*NCHUNK, 512, 0, stream>>>(gxH, gxV, qw0[0], qw0[1], dq0[0], dq0[1], F(19), F(27), y0H, y0V);
    gemm_bt<<<dim3(72,6,4), 256, 0, stream>>>(y0H, wih1c[0], F(22), gxH, 256, 768, zA1, zB1, 768, zC, nullptr, nullptr, 0);
    gemm_bt<<<dim3(72,6,4), 256, 0, stream>>>(y0V, wih1c[1], F(30), gxV, 256, 768, zA1, zB1, 768, zC, nullptr, nullptr, 0);
    gru_rec<<<16*NCHUNK, 512, 0, stream>>>(gxH, gxV, qw1[0], qw1[1], dq1[0], dq1[1], F(23), F(31), z1H, z1V);

    // ---- Stage B ----
    repack_B<<<18432, 256, 0, stream>>>(z1H, z1V, xh, xv);
    gemm_bt<<<dim3(72,6,4), 256, 0, stream>>>(xh, wih0c[2], F(34), gxH, 128, 768, zA0, zB0, 768, zC, nullptr, nullptr, 0);
    gemm_bt<<<dim3(72,6,4), 256, 0, stream>>>(xv, wih0c[3], F(42), gxV, 128, 768, zA0, zB0, 768, zC, nullptr, nullptr, 0);
    gru_rec<<<16*NCHUNK, 512, 0, stream>>>(gxH, gxV, qw0[2], qw0[3], dq0[2], dq0[3], F(35), F(43), y0H, y0V);
    gemm_bt<<<dim3(72,6,4), 256, 0, stream>>>(y0H, wih1c[2], F(38), gxH, 256, 768, zA1, zB1, 768, zC, nullptr, nullptr, 0);
    gemm_bt<<<dim3(72,6,4), 256, 0, stream>>>(y0V, wih1c[3], F(46), gxV, 256, 768, zA1, zB1, 768, zC, nullptr, nullptr, 0);
    gru_rec<<<16*NCHUNK, 512, 0, stream>>>(gxH, gxV, qw1[2], qw1[3], dq1[2], dq1[3], F(39), F(47), z1H, z1V);

    // ---- combine ----
    repack_comb<<<36864, 256, 0, stream>>>(z1H, z1V, Ac);
    gemm_bt<<<dim3(288,1,1), 256, 0, stream>>>(Ac, wcr, F(12), p3, 256, 128,
        0,0,0,0, F(13), stats + 128, 9216);
    make_ss<<<2, 256, 0, stream>>>(stats + 128, F(14), F(15), sc3, sh3, 1.f/147456.f);
    final_kernel<<<384, 256, 0, stream>>>(p3, sc3, sh3, (float*)d_out);
}

// Round 4
// 973.718 us; speedup vs baseline: 1.2780x; 1.2780x over previous
//
#include <hip/hip_runtime.h>

typedef unsigned short u16;
typedef __attribute__((ext_vector_type(8))) short bf16x8;
typedef __attribute__((ext_vector_type(4))) float f32x4;
typedef __attribute__((ext_vector_type(4))) int   i32x4;

#define DEVFN static __device__ __forceinline__
#define AS_G __attribute__((address_space(1)))
#define AS_L __attribute__((address_space(3)))

DEVFN float b2f(u16 u){ return __uint_as_float(((unsigned int)u)<<16); }
DEVFN u16 f2b(float f){ unsigned int x = __float_as_uint(f); x += 0x7FFFu + ((x>>16)&1u); return (u16)(x>>16); }
DEVFN float fastrcp(float x){ return __builtin_amdgcn_rcpf(x); }

// ---------------------------------------------------------------------------
// Batched fp32 -> bf16 cast: one launch for all 8 wih tensors (blockIdx.y=p).
// ---------------------------------------------------------------------------
struct CastArgs { const float* s[8]; u16* d[8]; int n[8]; };
__global__ void castf2b_g(CastArgs a)
{
    int p = blockIdx.y;
    int i = blockIdx.x*256 + threadIdx.x;
    if (i < a.n[p]) a.d[p][i] = f2b(a.s[p][i]);
}

// ---------------------------------------------------------------------------
// Batched whh fp32 -> i8 per-row quantization (blockIdx.y=p, 1 wave per row).
// ---------------------------------------------------------------------------
struct QuantArgs { const float* w[8]; char* q[8]; float* dq[8]; };
__global__ void quant_whh_g(QuantArgs a)
{
    int p = blockIdx.y;
    int row = blockIdx.x;
    int lane = threadIdx.x;
    const float* wr = a.w[p] + (long long)row*128;
    float v0 = wr[lane], v1 = wr[lane+64];
    float m = fmaxf(fabsf(v0), fabsf(v1));
#pragma unroll
    for (int off = 32; off; off >>= 1) m = fmaxf(m, __shfl_xor(m, off));
    float s = (m > 0.f) ? m * (1.f/127.f) : 1.f;
    float inv = 1.f / s;
    a.q[p][(long long)row*128 + lane]      = (char)__float2int_rn(v0 * inv);
    a.q[p][(long long)row*128 + lane + 64] = (char)__float2int_rn(v1 * inv);
    if (lane == 0) a.dq[p][row] = s * (1.f/127.f);
}

// ---------------------------------------------------------------------------
// Generic bf16 GEMM: C[M,N] = A[M,K] * B[N,K]^T (+bias[N]) (+PReLU) (+GN stats)
// Block remap: same-mTile blocks dispatch-adjacent for A-panel L2 reuse.
// ---------------------------------------------------------------------------
__global__ __launch_bounds__(256)
void gemm_bt(const u16* __restrict__ A, const u16* __restrict__ B,
             const float* __restrict__ bias, u16* __restrict__ C,
             int K, int N,
             long long zA, long long zB, long long zBias, long long zC,
             const float* __restrict__ alphaP, float* __restrict__ stats, int rowsPerB)
{
    __shared__ __align__(16) u16 As[128*32];
    __shared__ __align__(16) u16 Bs[128*32];
    __shared__ float sstat[16];

    const int tid  = threadIdx.x;
    const int wave = tid >> 6, lane = tid & 63;
    const int quad = lane >> 4, l16 = lane & 15;
    const int wm = wave & 1, wn = wave >> 1;
    const long long z = blockIdx.z;
    A += z * zA; B += z * zB; C += z * zC;
    if (bias) bias += z * zBias;
    const int lin   = blockIdx.y * gridDim.x + blockIdx.x;
    const int mBase = (int)(lin / gridDim.y) * 128;
    const int nBase = (int)(lin % gridDim.y) * 128;

    f32x4 acc[4][4];
#pragma unroll
    for (int i = 0; i < 4; i++)
#pragma unroll
        for (int j = 0; j < 4; j++) acc[i][j] = (f32x4){0.f,0.f,0.f,0.f};

    const int srow = lane >> 2;
    const int sk   = (lane & 3) * 8;
    const int nK = K >> 5;

    for (int kk = 0; kk < nK; ++kk) {
        const int k0 = kk << 5;
#pragma unroll
        for (int q = 0; q < 2; q++) {
            const u16* ga = A + (long long)(mBase + wave*32 + q*16 + srow) * K + k0 + sk;
            const u16* gb = B + (long long)(nBase + wave*32 + q*16 + srow) * K + k0 + sk;
            __builtin_amdgcn_global_load_lds((const AS_G unsigned int*)ga,
                (AS_L unsigned int*)(As + (wave*32 + q*16)*32), 16, 0, 0);
            __builtin_amdgcn_global_load_lds((const AS_G unsigned int*)gb,
                (AS_L unsigned int*)(Bs + (wave*32 + q*16)*32), 16, 0, 0);
        }
        __syncthreads();
        bf16x8 af[4], bfr[4];
#pragma unroll
        for (int mt = 0; mt < 4; mt++) af[mt]  = *(const bf16x8*)(As + (wm*64 + mt*16 + l16)*32 + quad*8);
#pragma unroll
        for (int nt = 0; nt < 4; nt++) bfr[nt] = *(const bf16x8*)(Bs + (wn*64 + nt*16 + l16)*32 + quad*8);
#pragma unroll
        for (int mt = 0; mt < 4; mt++)
#pragma unroll
            for (int nt = 0; nt < 4; nt++)
                acc[mt][nt] = __builtin_amdgcn_mfma_f32_16x16x32_bf16(af[mt], bfr[nt], acc[mt][nt], 0, 0, 0);
        __syncthreads();
    }

    const bool doStats = (stats != nullptr);
    const float alpha = alphaP ? alphaP[0] : 0.f;
    if (doStats) { if (tid < 16) sstat[tid] = 0.f; __syncthreads(); }

    float lsum[4] = {0,0,0,0}, lsq[4] = {0,0,0,0};
#pragma unroll
    for (int nt = 0; nt < 4; nt++) {
        const int col = nBase + wn*64 + nt*16 + l16;
        const float bv = bias ? bias[col] : 0.f;
#pragma unroll
        for (int mt = 0; mt < 4; mt++) {
#pragma unroll
            for (int r = 0; r < 4; r++) {
                const int row = mBase + wm*64 + mt*16 + quad*4 + r;
                float v = acc[mt][nt][r] + bv;
                if (alphaP) v = v > 0.f ? v : alpha * v;
                C[(long long)row * N + col] = f2b(v);
                lsum[nt] += v; lsq[nt] += v * v;
            }
        }
    }
    if (doStats) {
#pragma unroll
        for (int nt = 0; nt < 4; nt++) {
            const int gn = wn*4 + nt;
            atomicAdd(&sstat[gn], lsum[nt]);
            atomicAdd(&sstat[8 + gn], lsq[nt]);
        }
        __syncthreads();
        if (tid < 16) {
            const int b = mBase / rowsPerB;
            atomicAdd(&stats[b*16 + tid], sstat[tid]);
        }
    }
}

// ---------------------------------------------------------------------------
// GRU recurrence (i8 MFMA core), chunk-parallel.
// NCHUNK=16 -> 16 seqs x 16 chunks = 256 blocks = exactly #CUs (Round-2
// lesson: a second dispatch round does NOT overlap; balance the grid instead).
// CHUNK=144, WARM=112 (WARM+CHUNK=256 = 8*32 keeps the 32-step loop
// granularity; chunk 0 spans 144 = 4.5*32, handled by the < sEnd flush guard).
// Step body identical to the verified Round-1 version.
// ---------------------------------------------------------------------------
#define HSB 144     // h row stride in bytes (128 i8 + 16 pad, 16B aligned)
#define BURST 16
#define NCHUNK 16
#define CHUNK  144  // 2304 / NCHUNK
#define WARM   112  // warm-up steps; WARM + CHUNK multiple of 2*BURST

__global__ __launch_bounds__(512, 2)
void gru_rec(const u16* __restrict__ gxH, const u16* __restrict__ gxV,
             const char* __restrict__ qwH, const char* __restrict__ qwV,
             const float* __restrict__ dqH, const float* __restrict__ dqV,
             const float* __restrict__ bhhH, const float* __restrict__ bhhV,
             u16* __restrict__ outH, u16* __restrict__ outV)
{
    const int id    = blockIdx.x / NCHUNK;   // (stack, group, dir)
    const int chunk = blockIdx.x % NCHUNK;
    const int stack = id >> 3, g = (id >> 1) & 3, d = id & 1;
    const u16*  gx  = (stack ? gxV : gxH) + (long long)g*9216*768 + d*384;
    const char* qw  = (stack ? qwV : qwH) + (long long)(g*2 + d)*384*128;
    const float* dqv = (stack ? dqV : dqH) + (g*2 + d)*384;
    const float* bhh = (stack ? bhhV : bhhH) + (g*2 + d)*384;
    u16* out = (stack ? outV : outH) + (long long)g*9216*256 + d*128;

    const int sBegin = chunk * CHUNK;        // first step whose output we own
    const int sEnd   = sBegin + CHUNK;       // one past last
    const int sw     = (chunk == 0) ? 0 : sBegin - WARM;  // warm-up start

    const int tid = threadIdx.x;
    const int w = tid >> 6, lane = tid & 63;
    const int quad = lane >> 4, l16 = lane & 15;

    __shared__ __align__(16) char hbf8[2][16*HSB];   // 4.6 KB
    __shared__ __align__(16) u16 outs[2][BURST*512]; // 32 KB
    for (int i = tid; i < 2*16*HSB; i += 512) ((char*)hbf8)[i] = 0;

    const int col = w*16 + l16;
    i32x4 ifrag[3][2];
#pragma unroll
    for (int gate = 0; gate < 3; ++gate)
#pragma unroll
        for (int kc = 0; kc < 2; ++kc)
            ifrag[gate][kc] = *(const i32x4*)(qw + (long long)(gate*128 + col)*128 + kc*64 + quad*16);

    const float dqR = dqv[col], dqZ = dqv[128 + col], dqN = dqv[256 + col];
    const float bhr = bhh[col], bhz = bhh[128 + col], bhn = bhh[256 + col];
    float h = 0.f;

    const int step = d ? -1 : 1;
    const int t0 = d ? 2303 : 0;
    const long long rowStride = (long long)step * 3072;

    u16 bankA[BURST][3], bankB[BURST][3];
    const i32x4 zi = {0,0,0,0};

    auto loadBank = [&](u16 (&bk)[BURST][3], int sbase) {
        if (sbase >= sEnd) return;     // banks are 16-aligned: all-in or all-out
        const u16* p = gx + (long long)((t0 + step*sbase)*4 + quad)*768 + col;
#pragma unroll
        for (int j = 0; j < BURST; j++) {
            bk[j][0] = p[0]; bk[j][1] = p[128]; bk[j][2] = p[256];
            p += rowStride;
        }
    };

    auto flushOut = [&](int sbase, int bank) {
        const u16* ob = outs[bank];
#pragma unroll
        for (int c = 0; c < 2; c++) {
            const int lin = (tid + c*512) * 8;
            const int s   = lin >> 9;
            const int rem = lin & 511;
            const int q   = rem >> 7, cc = rem & 127;
            const int tt  = t0 + step * (sbase + s);
            *(uint4*)(out + (long long)(tt*4 + q)*256 + cc) = *(const uint4*)(ob + lin);
        }
    };

    auto stepf = [&](int j, int bank, u16 g0, u16 g1, u16 g2) {
        const char* hb = hbf8[j & 1];
        char* hw = (char*)hbf8[(j + 1) & 1];
        i32x4 a0 = *(const i32x4*)(hb + l16*HSB + quad*16);
        i32x4 a1 = *(const i32x4*)(hb + l16*HSB + 64 + quad*16);
        i32x4 aR = __builtin_amdgcn_mfma_i32_16x16x64_i8(a0, ifrag[0][0], zi, 0, 0, 0);
        i32x4 aZ = __builtin_amdgcn_mfma_i32_16x16x64_i8(a0, ifrag[1][0], zi, 0, 0, 0);
        i32x4 aN = __builtin_amdgcn_mfma_i32_16x16x64_i8(a0, ifrag[2][0], zi, 0, 0, 0);
        aR = __builtin_amdgcn_mfma_i32_16x16x64_i8(a1, ifrag[0][1], aR, 0, 0, 0);
        aZ = __builtin_amdgcn_mfma_i32_16x16x64_i8(a1, ifrag[1][1], aZ, 0, 0, 0);
        aN = __builtin_amdgcn_mfma_i32_16x16x64_i8(a1, ifrag[2][1], aN, 0, 0, 0);
        // lane reads C[row = 4*quad (reg 0)][col = l16] -> (batch quad, this col)
        float r  = fastrcp(1.f + __expf(-(b2f(g0) + bhr + (float)aR[0] * dqR)));
        float zz = fastrcp(1.f + __expf(-(b2f(g1) + bhz + (float)aZ[0] * dqZ)));
        float nn = b2f(g2) + r * ((float)aN[0] * dqN + bhn);
        nn = 1.f - 2.f * fastrcp(__expf(2.f * nn) + 1.f);   // tanh
        h = zz * (h - nn) + nn;
        hw[4*quad*HSB + col] = (char)__float2int_rn(h * 127.f);
        outs[bank][j*512 + quad*128 + col] = f2b(h);
        __syncthreads();
    };

    loadBank(bankA, sw);
    __syncthreads();   // hbf8 zero visible + bankA drained

    for (int base = sw; base < sEnd; base += 2*BURST) {
        loadBank(bankB, base + BURST);
#pragma unroll
        for (int j = 0; j < BURST; j++) stepf(j, 0, bankA[j][0], bankA[j][1], bankA[j][2]);
        if (base >= sBegin) flushOut(base, 0);               // base < sEnd by loop cond
        loadBank(bankA, base + 2*BURST);
#pragma unroll
        for (int j = 0; j < BURST; j++) stepf(j, 1, bankB[j][0], bankB[j][1], bankB[j][2]);
        const int b2s = base + BURST;
        if (b2s >= sBegin && b2s < sEnd) flushOut(b2s, 1);   // upper guard: chunk-0 tail
    }
}

// ---------------------------------------------------------------------------
// Small helper kernels (fp32 external boundaries)
// ---------------------------------------------------------------------------
__global__ void repack_w(const float* __restrict__ w1, const float* __restrict__ w2,
                         const float* __restrict__ wc,
                         u16* __restrict__ w1r, u16* __restrict__ w2r, u16* __restrict__ wcr)
{
    int idx = blockIdx.x*256 + threadIdx.x;
    if (idx < 128*1152) {
        int o = idx / 1152, k = idx % 1152, tap = k >> 7, ci = k & 127;
        w2r[idx] = f2b(w2[(o*128 + ci)*9 + tap]);
    }
    if (idx < 128*32) {
        int o = idx >> 5, k = idx & 31;
        float v = 0.f;
        if (k < 27) { int tap = k/3, ci = k - tap*3; v = w1[(o*3 + ci)*9 + tap]; }
        w1r[idx] = f2b(v);
    }
    if (idx < 128*256) wcr[idx] = f2b(wc[idx]);
}

__global__ void im2col1(const float* __restrict__ x, u16* __restrict__ A1)
{
    int row = blockIdx.x*256 + threadIdx.x;
    if (row >= 36864) return;
    int b = row / 9216, rem = row % 9216, m = rem / 96, n = rem % 96;
    u16* dst = A1 + (long long)row*32;
#pragma unroll
    for (int k = 0; k < 32; k++) {
        float v = 0.f;
        if (k < 27) {
            int tap = k/3, ci = k - tap*3;
            int mm = m + tap/3 - 1, nn = n + tap%3 - 1;
            if (mm >= 0 && mm < 96 && nn >= 0 && nn < 96)
                v = x[((b*3 + ci)*96 + mm)*96 + nn];
        }
        dst[k] = f2b(v);
    }
}

__global__ void make_ss(const float* __restrict__ stats, const float* __restrict__ gw,
                        const float* __restrict__ gb, float* __restrict__ sc,
                        float* __restrict__ sh, float invCnt)
{
    int idx = blockIdx.x*256 + threadIdx.x;
    if (idx >= 512) return;
    int b = idx >> 7, c = idx & 127, gn = c >> 4;
    float s = stats[b*16 + gn], q = stats[b*16 + 8 + gn];
    float mu = s * invCnt, var = fmaxf(q * invCnt - mu*mu, 0.f);
    float rstd = rsqrtf(var + 1e-5f);
    float scale = rstd * gw[c];
    sc[idx] = scale;
    sh[idx] = gb[c] - mu * scale;
}

// Vectorized x8: one thread = 8 channels of one (row, tap). 36864*144 threads.
__global__ void im2col2(const u16* __restrict__ buf1, const float* __restrict__ sc,
                        const float* __restrict__ sh, u16* __restrict__ A2)
{
    int idx = blockIdx.x*256 + threadIdx.x;     // 5,308,416 = 36864*144 exact
    int row = idx / 144, q = idx % 144;
    int tap = q >> 4, ci0 = (q & 15) << 3;
    int b = row / 9216, rem = row % 9216, m = rem / 96, n = rem % 96;
    int mm = m + tap/3 - 1, nn = n + tap%3 - 1;
    bf16x8 o = (bf16x8){0,0,0,0,0,0,0,0};
    if (mm >= 0 && mm < 96 && nn >= 0 && nn < 96) {
        bf16x8 v = *(const bf16x8*)(buf1 + (long long)(b*9216 + mm*96 + nn)*128 + ci0);
#pragma unroll
        for (int j = 0; j < 8; j++)
            o[j] = (short)f2b(b2f((u16)v[j]) * sc[b*128 + ci0 + j] + sh[b*128 + ci0 + j]);
    }
    *(bf16x8*)(A2 + (long long)row*1152 + tap*128 + ci0) = o;
}

// Vectorized x8. 589824 threads.
__global__ void repack_seq(const u16* __restrict__ buf2, const float* __restrict__ sc,
                           const float* __restrict__ sh, u16* __restrict__ xh, u16* __restrict__ xv)
{
    int idx = blockIdx.x*256 + threadIdx.x;
    int c0 = (idx & 15) << 3, r1 = idx >> 4;
    int b = r1 & 3, r2 = r1 >> 2;
    int t = r2 % 2304, g = r2 / 2304;
    int iw = t / 96, pos = t % 96;
    int rowH = b*9216 + (g*24 + iw)*96 + pos;
    int rowV = b*9216 + pos*96 + (g*24 + iw);
    bf16x8 vh = *(const bf16x8*)(buf2 + (long long)rowH*128 + c0);
    bf16x8 vv = *(const bf16x8*)(buf2 + (long long)rowV*128 + c0);
    bf16x8 oh, ov;
#pragma unroll
    for (int j = 0; j < 8; j++) {
        float scale = sc[b*128 + c0 + j], shift = sh[b*128 + c0 + j];
        oh[j] = (short)f2b(b2f((u16)vh[j]) * scale + shift);
        ov[j] = (short)f2b(b2f((u16)vv[j]) * scale + shift);
    }
    *(bf16x8*)(xh + ((long long)r1 << 7) + c0) = oh;
    *(bf16x8*)(xv + ((long long)r1 << 7) + c0) = ov;
}

// Vectorized x8. 589824 threads.
__global__ void repack_B(const u16* __restrict__ z1H, const u16* __restrict__ z1V,
                         u16* __restrict__ xh2, u16* __restrict__ xv2)
{
    int idx = blockIdx.x*256 + threadIdx.x;
    int c0 = (idx & 15) << 3, r1 = idx >> 4;
    int b = r1 & 3, r2 = r1 >> 2;
    int t = r2 % 2304, g = r2 / 2304;
    {
        int ih2 = t / 96, n = t % 96, gs = n / 24, iv = n % 24;
        long long s = ((long long)gs*9216 + (iv*96 + g*24 + ih2)*4 + b)*256 + c0;
        bf16x8 a = *(const bf16x8*)(z1V + s);
        bf16x8 bb = *(const bf16x8*)(z1V + s + 128);
        bf16x8 o;
#pragma unroll
        for (int j = 0; j < 8; j++) o[j] = (short)f2b(0.5f*(b2f((u16)a[j]) + b2f((u16)bb[j])));
        *(bf16x8*)(xh2 + ((long long)r1 << 7) + c0) = o;
    }
    {
        int iv = t / 96, m = t % 96, gs = m / 24, ih = m % 24;
        long long s = ((long long)gs*9216 + (ih*96 + g*24 + iv)*4 + b)*256 + c0;
        bf16x8 a = *(const bf16x8*)(z1H + s);
        bf16x8 bb = *(const bf16x8*)(z1H + s + 128);
        bf16x8 o;
#pragma unroll
        for (int j = 0; j < 8; j++) o[j] = (short)f2b(0.5f*(b2f((u16)a[j]) + b2f((u16)bb[j])));
        *(bf16x8*)(xv2 + ((long long)r1 << 7) + c0) = o;
    }
}

// Vectorized x8. 1,179,648 threads.
__global__ void repack_comb(const u16* __restrict__ z1H, const u16* __restrict__ z1V,
                            u16* __restrict__ Ac)
{
    int idx = blockIdx.x*256 + threadIdx.x;
    int k0 = (idx & 31) << 3;
    int row = idx >> 5;
    int b = row / 9216, rem = row % 9216, m = rem / 96, n = rem % 96;
    const u16* src;
    long long s;
    if (k0 < 128) {
        int g = m / 24, ih = m % 24, ts = ih*96 + n;
        s = ((long long)g*9216 + ts*4 + b)*256 + k0;
        src = z1H;
    } else {
        int c = k0 - 128, g = n / 24, iv = n % 24, ts = iv*96 + m;
        s = ((long long)g*9216 + ts*4 + b)*256 + c;
        src = z1V;
    }
    bf16x8 a = *(const bf16x8*)(src + s);
    bf16x8 bb = *(const bf16x8*)(src + s + 128);
    bf16x8 o;
#pragma unroll
    for (int j = 0; j < 8; j++) o[j] = (short)f2b(0.5f*(b2f((u16)a[j]) + b2f((u16)bb[j])));
    *(bf16x8*)(Ac + (long long)row*256 + k0) = o;
}

__global__ void final_kernel(const u16* __restrict__ p3, const float* __restrict__ sc,
                             const float* __restrict__ sh, float* __restrict__ out)
{
    __shared__ float tile[128*97];
    int bm = blockIdx.x;
    int b = bm / 96, m = bm % 96;
    int tid = threadIdx.x;
    int rowbase = b*9216 + m*96;
    for (int idx = tid; idx < 96*128; idx += 256) {
        int n = idx >> 7, o = idx & 127;
        float v = b2f(p3[(long long)(rowbase + n)*128 + o]);
        tile[o*97 + n] = v * sc[b*128 + o] + sh[b*128 + o];
    }
    __syncthreads();
    for (int idx = tid; idx < 96*128; idx += 256) {
        int o = idx / 96, n = idx % 96;
        out[((long long)(b*128 + o)*96 + m)*96 + n] = tile[o*97 + n];
    }
}

// ---------------------------------------------------------------------------
extern "C" void kernel_launch(void* const* d_in, const int* in_sizes, int n_in,
                              void* d_out, int out_size, void* d_ws, size_t ws_size,
                              hipStream_t stream)
{
    (void)in_sizes; (void)n_in; (void)out_size;
    auto F = [&](int i){ return (const float*)d_in[i]; };

    char* ws = (char*)d_ws;
    size_t off = 0;
    auto alloc = [&](size_t bytes)->char* {
        char* p = ws + off;
        off += (bytes + 255) & ~(size_t)255;
        return p;
    };

    float* stats = (float*)alloc(3*64*sizeof(float));
    float* sc1 = (float*)alloc(512*4); float* sh1 = (float*)alloc(512*4);
    float* sc2 = (float*)alloc(512*4); float* sh2 = (float*)alloc(512*4);
    float* sc3 = (float*)alloc(512*4); float* sh3 = (float*)alloc(512*4);
    u16* w1r  = (u16*)alloc((size_t)128*32*2);
    u16* w2r  = (u16*)alloc((size_t)128*1152*2);
    u16* wcr  = (u16*)alloc((size_t)128*256*2);
    u16 *wih0c[4], *wih1c[4];
    char *qw0[4], *qw1[4];
    float *dq0[4], *dq1[4];
    for (int p = 0; p < 4; p++) {
        wih0c[p] = (u16*)alloc((size_t)393216*2);
        wih1c[p] = (u16*)alloc((size_t)786432*2);
        qw0[p]   = (char*)alloc((size_t)393216);
        qw1[p]   = (char*)alloc((size_t)393216);
        dq0[p]   = (float*)alloc((size_t)3072*4);
        dq1[p]   = (float*)alloc((size_t)3072*4);
    }
    u16* A1   = (u16*)alloc((size_t)36864*32*2);
    u16* buf1 = (u16*)alloc((size_t)36864*128*2);
    u16* buf2 = (u16*)alloc((size_t)36864*128*2);
    u16* xh   = (u16*)alloc((size_t)4718592*2);
    u16* xv   = (u16*)alloc((size_t)4718592*2);
    u16* gxH  = (u16*)alloc((size_t)4*9216*768*2);
    u16* gxV  = (u16*)alloc((size_t)4*9216*768*2);
    u16* z1H  = (u16*)alloc((size_t)4*9216*256*2);
    u16* z1V  = (u16*)alloc((size_t)4*9216*256*2);

    u16* A2  = gxH;
    u16* y0H = xh;
    u16* y0V = buf1;
    u16* Ac  = xh;
    u16* p3  = buf1;

    if (ws_size < off) return;

    hipMemsetAsync(stats, 0, 3*64*sizeof(float), stream);
    repack_w<<<576, 256, 0, stream>>>(F(1), F(6), F(11), w1r, w2r, wcr);
    im2col1<<<144, 256, 0, stream>>>(F(0), A1);

    CastArgs ca;
    QuantArgs qa;
    for (int p = 0; p < 4; p++) {
        int base = 16 + p*8;
        ca.s[p]   = F(base+0); ca.d[p]   = wih0c[p]; ca.n[p]   = 393216;
        ca.s[p+4] = F(base+4); ca.d[p+4] = wih1c[p]; ca.n[p+4] = 786432;
        qa.w[p]   = F(base+1); qa.q[p]   = qw0[p];   qa.dq[p]   = dq0[p];
        qa.w[p+4] = F(base+5); qa.q[p+4] = qw1[p];   qa.dq[p+4] = dq1[p];
    }
    castf2b_g<<<dim3(3072, 8), 256, 0, stream>>>(ca);
    quant_whh_g<<<dim3(3072, 8), 64, 0, stream>>>(qa);

    gemm_bt<<<dim3(288,1,1), 256, 0, stream>>>(A1, w1r, F(2), buf1, 32, 128,
        0,0,0,0, F(3), stats + 0, 9216);
    make_ss<<<2, 256, 0, stream>>>(stats + 0, F(4), F(5), sc1, sh1, 1.f/147456.f);

    im2col2<<<20736, 256, 0, stream>>>(buf1, sc1, sh1, A2);
    gemm_bt<<<dim3(288,1,1), 256, 0, stream>>>(A2, w2r, F(7), buf2, 1152, 128,
        0,0,0,0, F(8), stats + 64, 9216);
    make_ss<<<2, 256, 0, stream>>>(stats + 64, F(9), F(10), sc2, sh2, 1.f/147456.f);

    repack_seq<<<2304, 256, 0, stream>>>(buf2, sc2, sh2, xh, xv);

    const long long zA0 = 9216LL*128, zA1 = 9216LL*256;
    const long long zB0 = 768LL*128,  zB1 = 768LL*256;
    const long long zC  = 9216LL*768;

    // ---- Stage A ----
    gemm_bt<<<dim3(72,6,4), 256, 0, stream>>>(xh, wih0c[0], F(18), gxH, 128, 768, zA0, zB0, 768, zC, nullptr, nullptr, 0);
    gemm_bt<<<dim3(72,6,4), 256, 0, stream>>>(xv, wih0c[1], F(26), gxV, 128, 768, zA0, zB0, 768, zC, nullptr, nullptr, 0);
    gru_rec<<<16*NCHUNK, 512, 0, stream>>>(gxH, gxV, qw0[0], qw0[1], dq0[0], dq0[1], F(19), F(27), y0H, y0V);
    gemm_bt<<<dim3(72,6,4), 256, 0, stream>>>(y0H, wih1c[0], F(22), gxH, 256, 768, zA1, zB1, 768, zC, nullptr, nullptr, 0);
    gemm_bt<<<dim3(72,6,4), 256, 0, stream>>>(y0V, wih1c[1], F(30), gxV, 256, 768, zA1, zB1, 768, zC, nullptr, nullptr, 0);
    gru_rec<<<16*NCHUNK, 512, 0, stream>>>(gxH, gxV, qw1[0], qw1[1], dq1[0], dq1[1], F(23), F(31), z1H, z1V);

    // ---- Stage B ----
    repack_B<<<2304, 256, 0, stream>>>(z1H, z1V, xh, xv);
    gemm_bt<<<dim3(72,6,4), 256, 0, stream>>>(xh, wih0c[2], F(34), gxH, 128, 768, zA0, zB0, 768, zC, nullptr, nullptr, 0);
    gemm_bt<<<dim3(72,6,4), 256, 0, stream>>>(xv, wih0c[3], F(42), gxV, 128, 768, zA0, zB0, 768, zC, nullptr, nullptr, 0);
    gru_rec<<<16*NCHUNK, 512, 0, stream>>>(gxH, gxV, qw0[2], qw0[3], dq0[2], dq0[3], F(35), F(43), y0H, y0V);
    gemm_bt<<<dim3(72,6,4), 256, 0, stream>>>(y0H, wih1c[2], F(38), gxH, 256, 768, zA1, zB1, 768, zC, nullptr, nullptr, 0);
    gemm_bt<<<dim3(72,6,4), 256, 0, stream>>>(y0V, wih1c[3], F(46), gxV, 256, 768, zA1, zB1, 768, zC, nullptr, nullptr, 0);
    gru_rec<<<16*NCHUNK, 512, 0, stream>>>(gxH, gxV, qw1[2], qw1[3], dq1[2], dq1[3], F(39), F(47), z1H, z1V);

    // ---- combine ----
    repack_comb<<<4608, 256, 0, stream>>>(z1H, z1V, Ac);
    gemm_bt<<<dim3(288,1,1), 256, 0, stream>>>(Ac, wcr, F(12), p3, 256, 128,
        0,0,0,0, F(13), stats + 128, 9216);
    make_ss<<<2, 256, 0, stream>>>(stats + 128, F(14), F(15), sc3, sh3, 1.f/147456.f);
    final_kernel<<<384, 256, 0, stream>>>(p3, sc3, sh3, (float*)d_out);
}

// Round 5
// 961.367 us; speedup vs baseline: 1.2944x; 1.0128x over previous
//
#include <hip/hip_runtime.h>

typedef unsigned short u16;
typedef __attribute__((ext_vector_type(8))) short bf16x8;
typedef __attribute__((ext_vector_type(4))) float f32x4;
typedef __attribute__((ext_vector_type(4))) int   i32x4;

#define DEVFN static __device__ __forceinline__
#define AS_G __attribute__((address_space(1)))
#define AS_L __attribute__((address_space(3)))

DEVFN float b2f(u16 u){ return __uint_as_float(((unsigned int)u)<<16); }
DEVFN u16 f2b(float f){ unsigned int x = __float_as_uint(f); x += 0x7FFFu + ((x>>16)&1u); return (u16)(x>>16); }
DEVFN float fastrcp(float x){ return __builtin_amdgcn_rcpf(x); }

// ---------------------------------------------------------------------------
// Batched fp32 -> bf16 cast: one launch for all 8 wih tensors (blockIdx.y=p).
// ---------------------------------------------------------------------------
struct CastArgs { const float* s[8]; u16* d[8]; int n[8]; };
__global__ void castf2b_g(CastArgs a)
{
    int p = blockIdx.y;
    int i = blockIdx.x*256 + threadIdx.x;
    if (i < a.n[p]) a.d[p][i] = f2b(a.s[p][i]);
}

// ---------------------------------------------------------------------------
// Batched whh fp32 -> i8 per-row quantization (blockIdx.y=p, 1 wave per row).
// ---------------------------------------------------------------------------
struct QuantArgs { const float* w[8]; char* q[8]; float* dq[8]; };
__global__ void quant_whh_g(QuantArgs a)
{
    int p = blockIdx.y;
    int row = blockIdx.x;
    int lane = threadIdx.x;
    const float* wr = a.w[p] + (long long)row*128;
    float v0 = wr[lane], v1 = wr[lane+64];
    float m = fmaxf(fabsf(v0), fabsf(v1));
#pragma unroll
    for (int off = 32; off; off >>= 1) m = fmaxf(m, __shfl_xor(m, off));
    float s = (m > 0.f) ? m * (1.f/127.f) : 1.f;
    float inv = 1.f / s;
    a.q[p][(long long)row*128 + lane]      = (char)__float2int_rn(v0 * inv);
    a.q[p][(long long)row*128 + lane + 64] = (char)__float2int_rn(v1 * inv);
    if (lane == 0) a.dq[p][row] = s * (1.f/127.f);
}

// ---------------------------------------------------------------------------
// Generic bf16 GEMM: C[M,N] = A[M,K] * B[N,K]^T (+bias[N]) (+PReLU) (+GN stats)
// - MFMA operands SWAPPED (mfma(bfr, af)): lane reg r holds 4 consecutive
//   COLS of one row -> C-write is 16x uint2 (8B) instead of 64x 2B stores.
//   A/B fragment lane layouts are identical, so the swap is exact.
// - Stats accumulation branched out for stats==nullptr (the 8 big GEMMs).
// - Optional second pointer set (Ax..Cx) selected for blockIdx.z >= zHalf:
//   merges the independent H/V GEMM pairs into one launch.
// ---------------------------------------------------------------------------
__global__ __launch_bounds__(256)
void gemm_bt(const u16* __restrict__ A, const u16* __restrict__ B,
             const float* __restrict__ bias, u16* __restrict__ C,
             int K, int N,
             long long zA, long long zB, long long zBias, long long zC,
             const float* __restrict__ alphaP, float* __restrict__ stats, int rowsPerB,
             const u16* __restrict__ Ax, const u16* __restrict__ Bx,
             const float* __restrict__ biasx, u16* __restrict__ Cx, int zHalf)
{
    __shared__ __align__(16) u16 As[128*32];
    __shared__ __align__(16) u16 Bs[128*32];
    __shared__ float sstat[16];

    const int tid  = threadIdx.x;
    const int wave = tid >> 6, lane = tid & 63;
    const int quad = lane >> 4, l16 = lane & 15;
    const int wm = wave & 1, wn = wave >> 1;

    long long z = blockIdx.z;
    const u16* Ap = A; const u16* Bp = B; const float* bp = bias; u16* Cp = C;
    if (Ax && z >= zHalf) { Ap = Ax; Bp = Bx; bp = biasx; Cp = Cx; z -= zHalf; }
    Ap += z * zA; Bp += z * zB; Cp += z * zC;
    if (bp) bp += z * zBias;

    // dispatch order is x-fastest; remap so blocks sharing an A-panel are
    // dispatch-adjacent -> same XCD L2.
    const int lin   = blockIdx.y * gridDim.x + blockIdx.x;
    const int mBase = (int)(lin / gridDim.y) * 128;
    const int nBase = (int)(lin % gridDim.y) * 128;

    f32x4 acc[4][4];
#pragma unroll
    for (int i = 0; i < 4; i++)
#pragma unroll
        for (int j = 0; j < 4; j++) acc[i][j] = (f32x4){0.f,0.f,0.f,0.f};

    const int srow = lane >> 2;
    const int sk   = (lane & 3) * 8;
    const int nK = K >> 5;

    for (int kk = 0; kk < nK; ++kk) {
        const int k0 = kk << 5;
#pragma unroll
        for (int q = 0; q < 2; q++) {
            const u16* ga = Ap + (long long)(mBase + wave*32 + q*16 + srow) * K + k0 + sk;
            const u16* gb = Bp + (long long)(nBase + wave*32 + q*16 + srow) * K + k0 + sk;
            __builtin_amdgcn_global_load_lds((const AS_G unsigned int*)ga,
                (AS_L unsigned int*)(As + (wave*32 + q*16)*32), 16, 0, 0);
            __builtin_amdgcn_global_load_lds((const AS_G unsigned int*)gb,
                (AS_L unsigned int*)(Bs + (wave*32 + q*16)*32), 16, 0, 0);
        }
        __syncthreads();
        bf16x8 af[4], bfr[4];
#pragma unroll
        for (int mt = 0; mt < 4; mt++) af[mt]  = *(const bf16x8*)(As + (wm*64 + mt*16 + l16)*32 + quad*8);
#pragma unroll
        for (int nt = 0; nt < 4; nt++) bfr[nt] = *(const bf16x8*)(Bs + (wn*64 + nt*16 + l16)*32 + quad*8);
#pragma unroll
        for (int mt = 0; mt < 4; mt++)
#pragma unroll
            for (int nt = 0; nt < 4; nt++)
                acc[mt][nt] = __builtin_amdgcn_mfma_f32_16x16x32_bf16(bfr[nt], af[mt], acc[mt][nt], 0, 0, 0);
        __syncthreads();
    }

    const bool doStats = (stats != nullptr);
    const float alpha = alphaP ? alphaP[0] : 0.f;
    if (doStats) { if (tid < 16) sstat[tid] = 0.f; __syncthreads(); }

    // Swapped layout: lane reg r holds C[row = mBase+wm*64+mt*16+l16]
    //                              [col = nBase+wn*64+nt*16+quad*4+r]
    float lsum[4] = {0,0,0,0}, lsq[4] = {0,0,0,0};
#pragma unroll
    for (int nt = 0; nt < 4; nt++) {
        const int col0 = nBase + wn*64 + nt*16 + quad*4;
        float4 bv4 = {0.f, 0.f, 0.f, 0.f};
        if (bp) bv4 = *(const float4*)(bp + col0);
#pragma unroll
        for (int mt = 0; mt < 4; mt++) {
            const int row = mBase + wm*64 + mt*16 + l16;
            float v0 = acc[mt][nt][0] + bv4.x;
            float v1 = acc[mt][nt][1] + bv4.y;
            float v2 = acc[mt][nt][2] + bv4.z;
            float v3 = acc[mt][nt][3] + bv4.w;
            if (alphaP) {
                v0 = v0 > 0.f ? v0 : alpha * v0;
                v1 = v1 > 0.f ? v1 : alpha * v1;
                v2 = v2 > 0.f ? v2 : alpha * v2;
                v3 = v3 > 0.f ? v3 : alpha * v3;
            }
            if (doStats) {
                lsum[nt] += v0 + v1 + v2 + v3;
                lsq[nt]  += v0*v0 + v1*v1 + v2*v2 + v3*v3;
            }
            uint2 pk;
            pk.x = (unsigned)f2b(v0) | ((unsigned)f2b(v1) << 16);
            pk.y = (unsigned)f2b(v2) | ((unsigned)f2b(v3) << 16);
            *(uint2*)(Cp + (long long)row * N + col0) = pk;
        }
    }
    if (doStats) {
#pragma unroll
        for (int nt = 0; nt < 4; nt++) {
            const int gn = wn*4 + nt;
            atomicAdd(&sstat[gn], lsum[nt]);
            atomicAdd(&sstat[8 + gn], lsq[nt]);
        }
        __syncthreads();
        if (tid < 16) {
            const int b = mBase / rowsPerB;
            atomicAdd(&stats[b*16 + tid], sstat[tid]);
        }
    }
}

// ---------------------------------------------------------------------------
// GRU recurrence (i8 MFMA core), chunk-parallel. 256 blocks = #CUs.
// Per-step sync is lgkmcnt-only (s_waitcnt lgkmcnt(0); s_barrier): does NOT
// drain vmcnt, so the 48 burst-prefetch loads issued in loadBank stay in
// flight across the 16-step burst (compiler inserts the vmcnt wait at first
// register use, next burst). __syncthreads would drain them at step 0.
// ---------------------------------------------------------------------------
#define HSB 144     // h row stride in bytes (128 i8 + 16 pad, 16B aligned)
#define BURST 16
#define NCHUNK 16
#define CHUNK  144  // 2304 / NCHUNK
#define WARM   112  // warm-up steps; WARM + CHUNK multiple of 2*BURST

__global__ __launch_bounds__(512, 2)
void gru_rec(const u16* __restrict__ gxH, const u16* __restrict__ gxV,
             const char* __restrict__ qwH, const char* __restrict__ qwV,
             const float* __restrict__ dqH, const float* __restrict__ dqV,
             const float* __restrict__ bhhH, const float* __restrict__ bhhV,
             u16* __restrict__ outH, u16* __restrict__ outV)
{
    const int id    = blockIdx.x / NCHUNK;   // (stack, group, dir)
    const int chunk = blockIdx.x % NCHUNK;
    const int stack = id >> 3, g = (id >> 1) & 3, d = id & 1;
    const u16*  gx  = (stack ? gxV : gxH) + (long long)g*9216*768 + d*384;
    const char* qw  = (stack ? qwV : qwH) + (long long)(g*2 + d)*384*128;
    const float* dqv = (stack ? dqV : dqH) + (g*2 + d)*384;
    const float* bhh = (stack ? bhhV : bhhH) + (g*2 + d)*384;
    u16* out = (stack ? outV : outH) + (long long)g*9216*256 + d*128;

    const int sBegin = chunk * CHUNK;        // first step whose output we own
    const int sEnd   = sBegin + CHUNK;       // one past last
    const int sw     = (chunk == 0) ? 0 : sBegin - WARM;  // warm-up start

    const int tid = threadIdx.x;
    const int w = tid >> 6, lane = tid & 63;
    const int quad = lane >> 4, l16 = lane & 15;

    __shared__ __align__(16) char hbf8[2][16*HSB];   // 4.6 KB
    __shared__ __align__(16) u16 outs[2][BURST*512]; // 32 KB
    for (int i = tid; i < 2*16*HSB; i += 512) ((char*)hbf8)[i] = 0;

    const int col = w*16 + l16;
    i32x4 ifrag[3][2];
#pragma unroll
    for (int gate = 0; gate < 3; ++gate)
#pragma unroll
        for (int kc = 0; kc < 2; ++kc)
            ifrag[gate][kc] = *(const i32x4*)(qw + (long long)(gate*128 + col)*128 + kc*64 + quad*16);

    const float dqR = dqv[col], dqZ = dqv[128 + col], dqN = dqv[256 + col];
    const float bhr = bhh[col], bhz = bhh[128 + col], bhn = bhh[256 + col];
    float h = 0.f;

    const int step = d ? -1 : 1;
    const int t0 = d ? 2303 : 0;
    const long long rowStride = (long long)step * 3072;

    u16 bankA[BURST][3], bankB[BURST][3];
    const i32x4 zi = {0,0,0,0};

    auto loadBank = [&](u16 (&bk)[BURST][3], int sbase) {
        if (sbase >= sEnd) return;     // banks are 16-aligned: all-in or all-out
        const u16* p = gx + (long long)((t0 + step*sbase)*4 + quad)*768 + col;
#pragma unroll
        for (int j = 0; j < BURST; j++) {
            bk[j][0] = p[0]; bk[j][1] = p[128]; bk[j][2] = p[256];
            p += rowStride;
        }
    };

    auto flushOut = [&](int sbase, int bank) {
        const u16* ob = outs[bank];
#pragma unroll
        for (int c = 0; c < 2; c++) {
            const int lin = (tid + c*512) * 8;
            const int s   = lin >> 9;
            const int rem = lin & 511;
            const int q   = rem >> 7, cc = rem & 127;
            const int tt  = t0 + step * (sbase + s);
            *(uint4*)(out + (long long)(tt*4 + q)*256 + cc) = *(const uint4*)(ob + lin);
        }
    };

    // LDS-only barrier: drains this wave's LDS ops, then workgroup barrier.
    // Deliberately does NOT drain vmcnt (burst prefetch stays in flight).
    auto ldsbar = [&]() {
        asm volatile("s_waitcnt lgkmcnt(0)\n\ts_barrier" ::: "memory");
    };

    auto stepf = [&](int j, int bank, u16 g0, u16 g1, u16 g2) {
        const char* hb = hbf8[j & 1];
        char* hw = (char*)hbf8[(j + 1) & 1];
        i32x4 a0 = *(const i32x4*)(hb + l16*HSB + quad*16);
        i32x4 a1 = *(const i32x4*)(hb + l16*HSB + 64 + quad*16);
        i32x4 aR = __builtin_amdgcn_mfma_i32_16x16x64_i8(a0, ifrag[0][0], zi, 0, 0, 0);
        i32x4 aZ = __builtin_amdgcn_mfma_i32_16x16x64_i8(a0, ifrag[1][0], zi, 0, 0, 0);
        i32x4 aN = __builtin_amdgcn_mfma_i32_16x16x64_i8(a0, ifrag[2][0], zi, 0, 0, 0);
        aR = __builtin_amdgcn_mfma_i32_16x16x64_i8(a1, ifrag[0][1], aR, 0, 0, 0);
        aZ = __builtin_amdgcn_mfma_i32_16x16x64_i8(a1, ifrag[1][1], aZ, 0, 0, 0);
        aN = __builtin_amdgcn_mfma_i32_16x16x64_i8(a1, ifrag[2][1], aN, 0, 0, 0);
        // lane reads C[row = 4*quad (reg 0)][col = l16] -> (batch quad, this col)
        float r  = fastrcp(1.f + __expf(-(b2f(g0) + bhr + (float)aR[0] * dqR)));
        float zz = fastrcp(1.f + __expf(-(b2f(g1) + bhz + (float)aZ[0] * dqZ)));
        float nn = b2f(g2) + r * ((float)aN[0] * dqN + bhn);
        nn = 1.f - 2.f * fastrcp(__expf(2.f * nn) + 1.f);   // tanh
        h = zz * (h - nn) + nn;
        hw[4*quad*HSB + col] = (char)__float2int_rn(h * 127.f);
        outs[bank][j*512 + quad*128 + col] = f2b(h);
        ldsbar();
    };

    loadBank(bankA, sw);
    __syncthreads();   // hbf8 zero visible + bankA drained

    for (int base = sw; base < sEnd; base += 2*BURST) {
        loadBank(bankB, base + BURST);
#pragma unroll
        for (int j = 0; j < BURST; j++) stepf(j, 0, bankA[j][0], bankA[j][1], bankA[j][2]);
        if (base >= sBegin) flushOut(base, 0);               // base < sEnd by loop cond
        loadBank(bankA, base + 2*BURST);
#pragma unroll
        for (int j = 0; j < BURST; j++) stepf(j, 1, bankB[j][0], bankB[j][1], bankB[j][2]);
        const int b2s = base + BURST;
        if (b2s >= sBegin && b2s < sEnd) flushOut(b2s, 1);   // upper guard: chunk-0 tail
    }
}

// ---------------------------------------------------------------------------
// Small helper kernels (fp32 external boundaries)
// ---------------------------------------------------------------------------
__global__ void repack_w(const float* __restrict__ w1, const float* __restrict__ w2,
                         const float* __restrict__ wc,
                         u16* __restrict__ w1r, u16* __restrict__ w2r, u16* __restrict__ wcr)
{
    int idx = blockIdx.x*256 + threadIdx.x;
    if (idx < 128*1152) {
        int o = idx / 1152, k = idx % 1152, tap = k >> 7, ci = k & 127;
        w2r[idx] = f2b(w2[(o*128 + ci)*9 + tap]);
    }
    if (idx < 128*32) {
        int o = idx >> 5, k = idx & 31;
        float v = 0.f;
        if (k < 27) { int tap = k/3, ci = k - tap*3; v = w1[(o*3 + ci)*9 + tap]; }
        w1r[idx] = f2b(v);
    }
    if (idx < 128*256) wcr[idx] = f2b(wc[idx]);
}

__global__ void im2col1(const float* __restrict__ x, u16* __restrict__ A1)
{
    int row = blockIdx.x*256 + threadIdx.x;
    if (row >= 36864) return;
    int b = row / 9216, rem = row % 9216, m = rem / 96, n = rem % 96;
    u16* dst = A1 + (long long)row*32;
#pragma unroll
    for (int k = 0; k < 32; k++) {
        float v = 0.f;
        if (k < 27) {
            int tap = k/3, ci = k - tap*3;
            int mm = m + tap/3 - 1, nn = n + tap%3 - 1;
            if (mm >= 0 && mm < 96 && nn >= 0 && nn < 96)
                v = x[((b*3 + ci)*96 + mm)*96 + nn];
        }
        dst[k] = f2b(v);
    }
}

__global__ void make_ss(const float* __restrict__ stats, const float* __restrict__ gw,
                        const float* __restrict__ gb, float* __restrict__ sc,
                        float* __restrict__ sh, float invCnt)
{
    int idx = blockIdx.x*256 + threadIdx.x;
    if (idx >= 512) return;
    int b = idx >> 7, c = idx & 127, gn = c >> 4;
    float s = stats[b*16 + gn], q = stats[b*16 + 8 + gn];
    float mu = s * invCnt, var = fmaxf(q * invCnt - mu*mu, 0.f);
    float rstd = rsqrtf(var + 1e-5f);
    float scale = rstd * gw[c];
    sc[idx] = scale;
    sh[idx] = gb[c] - mu * scale;
}

// Vectorized x8: one thread = 8 channels of one (row, tap). 36864*144 threads.
__global__ void im2col2(const u16* __restrict__ buf1, const float* __restrict__ sc,
                        const float* __restrict__ sh, u16* __restrict__ A2)
{
    int idx = blockIdx.x*256 + threadIdx.x;     // 5,308,416 = 36864*144 exact
    int row = idx / 144, q = idx % 144;
    int tap = q >> 4, ci0 = (q & 15) << 3;
    int b = row / 9216, rem = row % 9216, m = rem / 96, n = rem % 96;
    int mm = m + tap/3 - 1, nn = n + tap%3 - 1;
    bf16x8 o = (bf16x8){0,0,0,0,0,0,0,0};
    if (mm >= 0 && mm < 96 && nn >= 0 && nn < 96) {
        bf16x8 v = *(const bf16x8*)(buf1 + (long long)(b*9216 + mm*96 + nn)*128 + ci0);
#pragma unroll
        for (int j = 0; j < 8; j++)
            o[j] = (short)f2b(b2f((u16)v[j]) * sc[b*128 + ci0 + j] + sh[b*128 + ci0 + j]);
    }
    *(bf16x8*)(A2 + (long long)row*1152 + tap*128 + ci0) = o;
}

// Vectorized x8. 589824 threads.
__global__ void repack_seq(const u16* __restrict__ buf2, const float* __restrict__ sc,
                           const float* __restrict__ sh, u16* __restrict__ xh, u16* __restrict__ xv)
{
    int idx = blockIdx.x*256 + threadIdx.x;
    int c0 = (idx & 15) << 3, r1 = idx >> 4;
    int b = r1 & 3, r2 = r1 >> 2;
    int t = r2 % 2304, g = r2 / 2304;
    int iw = t / 96, pos = t % 96;
    int rowH = b*9216 + (g*24 + iw)*96 + pos;
    int rowV = b*9216 + pos*96 + (g*24 + iw);
    bf16x8 vh = *(const bf16x8*)(buf2 + (long long)rowH*128 + c0);
    bf16x8 vv = *(const bf16x8*)(buf2 + (long long)rowV*128 + c0);
    bf16x8 oh, ov;
#pragma unroll
    for (int j = 0; j < 8; j++) {
        float scale = sc[b*128 + c0 + j], shift = sh[b*128 + c0 + j];
        oh[j] = (short)f2b(b2f((u16)vh[j]) * scale + shift);
        ov[j] = (short)f2b(b2f((u16)vv[j]) * scale + shift);
    }
    *(bf16x8*)(xh + ((long long)r1 << 7) + c0) = oh;
    *(bf16x8*)(xv + ((long long)r1 << 7) + c0) = ov;
}

// Vectorized x8. 589824 threads.
__global__ void repack_B(const u16* __restrict__ z1H, const u16* __restrict__ z1V,
                         u16* __restrict__ xh2, u16* __restrict__ xv2)
{
    int idx = blockIdx.x*256 + threadIdx.x;
    int c0 = (idx & 15) << 3, r1 = idx >> 4;
    int b = r1 & 3, r2 = r1 >> 2;
    int t = r2 % 2304, g = r2 / 2304;
    {
        int ih2 = t / 96, n = t % 96, gs = n / 24, iv = n % 24;
        long long s = ((long long)gs*9216 + (iv*96 + g*24 + ih2)*4 + b)*256 + c0;
        bf16x8 a = *(const bf16x8*)(z1V + s);
        bf16x8 bb = *(const bf16x8*)(z1V + s + 128);
        bf16x8 o;
#pragma unroll
        for (int j = 0; j < 8; j++) o[j] = (short)f2b(0.5f*(b2f((u16)a[j]) + b2f((u16)bb[j])));
        *(bf16x8*)(xh2 + ((long long)r1 << 7) + c0) = o;
    }
    {
        int iv = t / 96, m = t % 96, gs = m / 24, ih = m % 24;
        long long s = ((long long)gs*9216 + (ih*96 + g*24 + iv)*4 + b)*256 + c0;
        bf16x8 a = *(const bf16x8*)(z1H + s);
        bf16x8 bb = *(const bf16x8*)(z1H + s + 128);
        bf16x8 o;
#pragma unroll
        for (int j = 0; j < 8; j++) o[j] = (short)f2b(0.5f*(b2f((u16)a[j]) + b2f((u16)bb[j])));
        *(bf16x8*)(xv2 + ((long long)r1 << 7) + c0) = o;
    }
}

// Vectorized x8. 1,179,648 threads.
__global__ void repack_comb(const u16* __restrict__ z1H, const u16* __restrict__ z1V,
                            u16* __restrict__ Ac)
{
    int idx = blockIdx.x*256 + threadIdx.x;
    int k0 = (idx & 31) << 3;
    int row = idx >> 5;
    int b = row / 9216, rem = row % 9216, m = rem / 96, n = rem % 96;
    const u16* src;
    long long s;
    if (k0 < 128) {
        int g = m / 24, ih = m % 24, ts = ih*96 + n;
        s = ((long long)g*9216 + ts*4 + b)*256 + k0;
        src = z1H;
    } else {
        int c = k0 - 128, g = n / 24, iv = n % 24, ts = iv*96 + m;
        s = ((long long)g*9216 + ts*4 + b)*256 + c;
        src = z1V;
    }
    bf16x8 a = *(const bf16x8*)(src + s);
    bf16x8 bb = *(const bf16x8*)(src + s + 128);
    bf16x8 o;
#pragma unroll
    for (int j = 0; j < 8; j++) o[j] = (short)f2b(0.5f*(b2f((u16)a[j]) + b2f((u16)bb[j])));
    *(bf16x8*)(Ac + (long long)row*256 + k0) = o;
}

__global__ void final_kernel(const u16* __restrict__ p3, const float* __restrict__ sc,
                             const float* __restrict__ sh, float* __restrict__ out)
{
    __shared__ float tile[128*97];
    int bm = blockIdx.x;
    int b = bm / 96, m = bm % 96;
    int tid = threadIdx.x;
    int rowbase = b*9216 + m*96;
    for (int idx = tid; idx < 96*128; idx += 256) {
        int n = idx >> 7, o = idx & 127;
        float v = b2f(p3[(long long)(rowbase + n)*128 + o]);
        tile[o*97 + n] = v * sc[b*128 + o] + sh[b*128 + o];
    }
    __syncthreads();
    for (int idx = tid; idx < 96*128; idx += 256) {
        int o = idx / 96, n = idx % 96;
        out[((long long)(b*128 + o)*96 + m)*96 + n] = tile[o*97 + n];
    }
}

// ---------------------------------------------------------------------------
extern "C" void kernel_launch(void* const* d_in, const int* in_sizes, int n_in,
                              void* d_out, int out_size, void* d_ws, size_t ws_size,
                              hipStream_t stream)
{
    (void)in_sizes; (void)n_in; (void)out_size;
    auto F = [&](int i){ return (const float*)d_in[i]; };

    char* ws = (char*)d_ws;
    size_t off = 0;
    auto alloc = [&](size_t bytes)->char* {
        char* p = ws + off;
        off += (bytes + 255) & ~(size_t)255;
        return p;
    };

    float* stats = (float*)alloc(3*64*sizeof(float));
    float* sc1 = (float*)alloc(512*4); float* sh1 = (float*)alloc(512*4);
    float* sc2 = (float*)alloc(512*4); float* sh2 = (float*)alloc(512*4);
    float* sc3 = (float*)alloc(512*4); float* sh3 = (float*)alloc(512*4);
    u16* w1r  = (u16*)alloc((size_t)128*32*2);
    u16* w2r  = (u16*)alloc((size_t)128*1152*2);
    u16* wcr  = (u16*)alloc((size_t)128*256*2);
    u16 *wih0c[4], *wih1c[4];
    char *qw0[4], *qw1[4];
    float *dq0[4], *dq1[4];
    for (int p = 0; p < 4; p++) {
        wih0c[p] = (u16*)alloc((size_t)393216*2);
        wih1c[p] = (u16*)alloc((size_t)786432*2);
        qw0[p]   = (char*)alloc((size_t)393216);
        qw1[p]   = (char*)alloc((size_t)393216);
        dq0[p]   = (float*)alloc((size_t)3072*4);
        dq1[p]   = (float*)alloc((size_t)3072*4);
    }
    u16* A1   = (u16*)alloc((size_t)36864*32*2);
    u16* buf1 = (u16*)alloc((size_t)36864*128*2);
    u16* buf2 = (u16*)alloc((size_t)36864*128*2);
    u16* xh   = (u16*)alloc((size_t)4718592*2);
    u16* xv   = (u16*)alloc((size_t)4718592*2);
    u16* gxH  = (u16*)alloc((size_t)4*9216*768*2);
    u16* gxV  = (u16*)alloc((size_t)4*9216*768*2);
    u16* z1H  = (u16*)alloc((size_t)4*9216*256*2);
    u16* z1V  = (u16*)alloc((size_t)4*9216*256*2);

    u16* A2  = gxH;
    u16* y0H = xh;
    u16* y0V = buf1;
    u16* Ac  = xh;
    u16* p3  = buf1;

    if (ws_size < off) return;

    hipMemsetAsync(stats, 0, 3*64*sizeof(float), stream);
    repack_w<<<576, 256, 0, stream>>>(F(1), F(6), F(11), w1r, w2r, wcr);
    im2col1<<<144, 256, 0, stream>>>(F(0), A1);

    CastArgs ca;
    QuantArgs qa;
    for (int p = 0; p < 4; p++) {
        int base = 16 + p*8;
        ca.s[p]   = F(base+0); ca.d[p]   = wih0c[p]; ca.n[p]   = 393216;
        ca.s[p+4] = F(base+4); ca.d[p+4] = wih1c[p]; ca.n[p+4] = 786432;
        qa.w[p]   = F(base+1); qa.q[p]   = qw0[p];   qa.dq[p]   = dq0[p];
        qa.w[p+4] = F(base+5); qa.q[p+4] = qw1[p];   qa.dq[p+4] = dq1[p];
    }
    castf2b_g<<<dim3(3072, 8), 256, 0, stream>>>(ca);
    quant_whh_g<<<dim3(3072, 8), 64, 0, stream>>>(qa);

    gemm_bt<<<dim3(288,1,1), 256, 0, stream>>>(A1, w1r, F(2), buf1, 32, 128,
        0,0,0,0, F(3), stats + 0, 9216, nullptr, nullptr, nullptr, nullptr, 0);
    make_ss<<<2, 256, 0, stream>>>(stats + 0, F(4), F(5), sc1, sh1, 1.f/147456.f);

    im2col2<<<20736, 256, 0, stream>>>(buf1, sc1, sh1, A2);
    gemm_bt<<<dim3(288,1,1), 256, 0, stream>>>(A2, w2r, F(7), buf2, 1152, 128,
        0,0,0,0, F(8), stats + 64, 9216, nullptr, nullptr, nullptr, nullptr, 0);
    make_ss<<<2, 256, 0, stream>>>(stats + 64, F(9), F(10), sc2, sh2, 1.f/147456.f);

    repack_seq<<<2304, 256, 0, stream>>>(buf2, sc2, sh2, xh, xv);

    const long long zA0 = 9216LL*128, zA1 = 9216LL*256;
    const long long zB0 = 768LL*128,  zB1 = 768LL*256;
    const long long zC  = 9216LL*768;

    // ---- Stage A ---- (H and V pairs merged into single launches, z=8)
    gemm_bt<<<dim3(72,6,8), 256, 0, stream>>>(xh, wih0c[0], F(18), gxH, 128, 768, zA0, zB0, 768, zC,
        nullptr, nullptr, 0, xv, wih0c[1], F(26), gxV, 4);
    gru_rec<<<16*NCHUNK, 512, 0, stream>>>(gxH, gxV, qw0[0], qw0[1], dq0[0], dq0[1], F(19), F(27), y0H, y0V);
    gemm_bt<<<dim3(72,6,8), 256, 0, stream>>>(y0H, wih1c[0], F(22), gxH, 256, 768, zA1, zB1, 768, zC,
        nullptr, nullptr, 0, y0V, wih1c[1], F(30), gxV, 4);
    gru_rec<<<16*NCHUNK, 512, 0, stream>>>(gxH, gxV, qw1[0], qw1[1], dq1[0], dq1[1], F(23), F(31), z1H, z1V);

    // ---- Stage B ----
    repack_B<<<2304, 256, 0, stream>>>(z1H, z1V, xh, xv);
    gemm_bt<<<dim3(72,6,8), 256, 0, stream>>>(xh, wih0c[2], F(34), gxH, 128, 768, zA0, zB0, 768, zC,
        nullptr, nullptr, 0, xv, wih0c[3], F(42), gxV, 4);
    gru_rec<<<16*NCHUNK, 512, 0, stream>>>(gxH, gxV, qw0[2], qw0[3], dq0[2], dq0[3], F(35), F(43), y0H, y0V);
    gemm_bt<<<dim3(72,6,8), 256, 0, stream>>>(y0H, wih1c[2], F(38), gxH, 256, 768, zA1, zB1, 768, zC,
        nullptr, nullptr, 0, y0V, wih1c[3], F(46), gxV, 4);
    gru_rec<<<16*NCHUNK, 512, 0, stream>>>(gxH, gxV, qw1[2], qw1[3], dq1[2], dq1[3], F(39), F(47), z1H, z1V);

    // ---- combine ----
    repack_comb<<<4608, 256, 0, stream>>>(z1H, z1V, Ac);
    gemm_bt<<<dim3(288,1,1), 256, 0, stream>>>(Ac, wcr, F(12), p3, 256, 128,
        0,0,0,0, F(13), stats + 128, 9216, nullptr, nullptr, nullptr, nullptr, 0);
    make_ss<<<2, 256, 0, stream>>>(stats + 128, F(14), F(15), sc3, sh3, 1.f/147456.f);
    final_kernel<<<384, 256, 0, stream>>>(p3, sc3, sh3, (float*)d_out);
}